// Round 9
// baseline (150.396 us; speedup 1.0000x reference)
//
#include <hip/hip_runtime.h>
#include <hip/hip_bf16.h>

// Problem constants
#define BATCH 16
#define CH    32      // depthwise group count
#define CIN   64
#define OUTC  64
#define HH    128     // h after stride-2 stem
#define WW    128
#define HW    (HH * WW)
#define MHW   65536   // mas plane 256*256

typedef __attribute__((ext_vector_type(8))) short bf16x8;
typedef __attribute__((ext_vector_type(4))) float f32x4;

__device__ inline unsigned short bf16u(float x) {
  union { __hip_bfloat16 h; unsigned short s; } u;
  u.h = __float2bfloat16(x);
  return u.s;
}
__device__ inline unsigned int pack2(float lo, float hi) {
  return (unsigned int)bf16u(lo) | ((unsigned int)bf16u(hi) << 16);
}

// ---------------------------------------------------------------------------
// Kernel 0: weight prep (bf16 MFMA A-fragments).
//  - wfrag  [9][2][64][8]: stem w_inp
//  - wfrag2 [4][4][64][8]: final GEMM K=128 (k<64 sq, k>=64 cen)
//  - wfrag3 [9][4][64][8]: folded dout conv W9[tap][o][C]
//  - wfrag4 [9][4][64][8]: folded G1 conv  (w1; nonzero only C'==m>>1)
//  - wfrag5 [9][4][64][8]: folded G2 conv  (w2)
// ---------------------------------------------------------------------------
__global__ __launch_bounds__(256) void k_prep_weights(
    const float* __restrict__ w_out, const float* __restrict__ w_inp,
    const float* __restrict__ w1, const float* __restrict__ w2,
    const float* __restrict__ w3,
    unsigned short* __restrict__ wfrag, unsigned short* __restrict__ wfrag2,
    unsigned short* __restrict__ wfrag3, unsigned short* __restrict__ wfrag4,
    unsigned short* __restrict__ wfrag5) {
  const int kmap[9] = {0, 1, 2, 7, -1, 3, 6, 5, 4};
  int t = blockIdx.x * 256 + threadIdx.x;
  if (t < 9216) {
    int e    = t & 7;
    int lane = (t >> 3) & 63;
    int ct   = (t >> 9) & 1;
    int tap  = t >> 10;
    int co = ct * 16 + (lane & 15);
    int ci = (lane >> 4) * 8 + e;
    wfrag[t] = bf16u(w_inp[(co * CH + ci) * 9 + tap]);
  }
  int t2 = t - 9216;
  if (t2 >= 0 && t2 < 8192) {
    int e    = t2 & 7;
    int lane = (t2 >> 3) & 63;
    int ot   = (t2 >> 9) & 3;
    int kt   = t2 >> 11;
    int o = ot * 16 + (lane & 15);
    int k = kt * 32 + (lane >> 4) * 8 + e;
    int col = (k < 64) ? k : 64 + k;   // sq block 0..63, cen block 128..191
    wfrag2[t2] = bf16u(w_out[o * 192 + col]);
  }
  int t3 = t - 17408;
  if (t3 >= 0 && t3 < 18432) {
    int e    = t3 & 7;
    int lane = (t3 >> 3) & 63;
    int ot   = (t3 >> 9) & 3;
    int tap  = t3 >> 11;
    int o = ot * 16 + (lane & 15);
    int C = (lane >> 4) * 8 + e;
    float v = 0.f;
    if (tap == 4) {
      for (int k = 0; k < 8; ++k)
        for (int op = 0; op < 2; ++op)
          v += w_out[o * 192 + 64 + 2 * C + op] * w3[C * 16 + op * 8 + k];
    } else {
      int k = kmap[tap];
      for (int op = 0; op < 2; ++op)
        v -= w_out[o * 192 + 64 + 2 * C + op] * w3[C * 16 + op * 8 + k];
    }
    wfrag3[t3] = bf16u(v);
  }
  int t4 = t - 35840;
  if (t4 >= 0 && t4 < 18432) {
    int e    = t4 & 7;
    int lane = (t4 >> 3) & 63;
    int ot   = (t4 >> 9) & 3;
    int tap  = t4 >> 11;
    int m  = ot * 16 + (lane & 15);    // gate output channel 0..63
    int Cp = (lane >> 4) * 8 + e;      // x channel (K-dim)
    int C = m >> 1, op = m & 1;
    float v = 0.f;
    if (Cp == C) {
      if (tap == 4) {
        for (int k = 0; k < 8; ++k) v += w1[C * 16 + op * 8 + k];
      } else {
        v = -w1[C * 16 + op * 8 + kmap[tap]];
      }
    }
    wfrag4[t4] = bf16u(v);
  }
  int t5 = t - 54272;
  if (t5 >= 0 && t5 < 18432) {
    int e    = t5 & 7;
    int lane = (t5 >> 3) & 63;
    int ot   = (t5 >> 9) & 3;
    int tap  = t5 >> 11;
    int m  = ot * 16 + (lane & 15);
    int Cp = (lane >> 4) * 8 + e;
    int C = m >> 1, op = m & 1;
    float v = 0.f;
    if (Cp == C) {
      if (tap == 4) {
        for (int k = 0; k < 8; ++k) v += w2[C * 16 + op * 8 + k];
      } else {
        v = -w2[C * 16 + op * 8 + kmap[tap]];
      }
    }
    wfrag5[t5] = bf16u(v);
  }
}

// ---------------------------------------------------------------------------
// Kernel 1 v3: stem via bf16 MFMA (unchanged from round 7).
// ---------------------------------------------------------------------------
#define BEE 0
#define BEO 165
#define BOE 330
#define BOO 462
#define SPITCH 36

__global__ __launch_bounds__(256, 3) void k_stem(
    const float* __restrict__ mas, const unsigned short* __restrict__ wfrag,
    const float* __restrict__ b_inp, unsigned short* __restrict__ xbuf) {
  __shared__ alignas(16) unsigned short xs[594 * SPITCH];

  const int bx = blockIdx.x;   // 0..3   (col tiles of 32)
  const int by = blockIdx.y;   // 0..31  (row tiles of 4)
  const int b  = blockIdx.z;
  const int t  = threadIdx.x;
  const int lane = t & 63;
  const int w = t >> 6;
  const int ct = w >> 1, chh = w & 1;

  const int I0 = by * 4, J0 = bx * 32;
  const int R0 = 2 * I0 - 1, C0 = 2 * J0 - 1;

  bf16x8 af[9];
#pragma unroll
  for (int tap = 0; tap < 9; ++tap)
    af[tap] = ((const bf16x8*)wfrag)[(tap * 2 + ct) * 64 + lane];

  if (t < 144) {
    int chunk = t / 9, rr = t % 9;
    int cc0 = 1 + 4 * chunk;
    int ir = R0 + rr;
    bool vrow = (ir >= 0);
    const float* gp = mas + (size_t)b * CH * MHW +
                      (size_t)(vrow ? ir : 0) * 256 + (C0 + cc0);
    int off[4];
#pragma unroll
    for (int j = 0; j < 4; ++j) {
      int cc = cc0 + j;
      int r2 = rr >> 1;
      int pix;
      if (!(rr & 1))
        pix = (cc & 1) ? BEO + r2 * 33 + ((cc - 1) >> 1)
                       : BEE + r2 * 33 + (cc >> 1);
      else
        pix = (cc & 1) ? BOO + r2 * 33 + ((cc - 1) >> 1)
                       : BOE + r2 * 33 + (cc >> 1);
      off[j] = pix * SPITCH;
    }
#pragma unroll 4
    for (int q = 0; q < 16; ++q) {
      float4 v0 = make_float4(0.f, 0.f, 0.f, 0.f);
      float4 v1 = v0;
      if (vrow) {
        v0 = *(const float4*)(gp + (size_t)(2 * q) * MHW);
        v1 = *(const float4*)(gp + (size_t)(2 * q + 1) * MHW);
      }
      *(unsigned*)&xs[off[0] + 2 * q] = pack2(v0.x, v1.x);
      *(unsigned*)&xs[off[1] + 2 * q] = pack2(v0.y, v1.y);
      *(unsigned*)&xs[off[2] + 2 * q] = pack2(v0.z, v1.z);
      *(unsigned*)&xs[off[3] + 2 * q] = pack2(v0.w, v1.w);
    }
  } else if (t < 153) {
    int rr = t - 144;
    int ir = R0 + rr;
    bool ok = (ir >= 0) && (bx > 0);
    int r2 = rr >> 1;
    int pix = (rr & 1) ? (BOE + r2 * 33) : (BEE + r2 * 33);
    const float* gp = mas + (size_t)b * CH * MHW +
                      (size_t)(ir >= 0 ? ir : 0) * 256 + (C0 >= 0 ? C0 : 0);
    int off0 = pix * SPITCH;
#pragma unroll 4
    for (int q = 0; q < 16; ++q) {
      float a0 = 0.f, a1 = 0.f;
      if (ok) {
        a0 = gp[(size_t)(2 * q) * MHW];
        a1 = gp[(size_t)(2 * q + 1) * MHW];
      }
      *(unsigned*)&xs[off0 + 2 * q] = pack2(a0, a1);
    }
  }
  __syncthreads();

  f32x4 acc[4];
#pragma unroll
  for (int il = 0; il < 4; ++il) acc[il] = 0.f;

  const int jt = chh * 16 + (lane & 15);
  const int gsh = (lane >> 4) * 8;

#pragma unroll
  for (int ky = 0; ky < 3; ++ky) {
#pragma unroll
    for (int kx = 0; kx < 3; ++kx) {
      const int tap = ky * 3 + kx;
#pragma unroll
      for (int il = 0; il < 4; ++il) {
        int pix;
        if (ky == 1) {
          pix = (kx == 1) ? (BOO + il * 33 + jt)
                          : (BOE + il * 33 + jt + (kx == 2));
        } else {
          int r2 = il + (ky >> 1);
          pix = (kx == 1) ? (BEO + r2 * 33 + jt)
                          : (BEE + r2 * 33 + jt + (kx == 2));
        }
        bf16x8 bfr = *(const bf16x8*)(xs + pix * SPITCH + gsh);
        acc[il] = __builtin_amdgcn_mfma_f32_16x16x32_bf16(
            af[tap], bfr, acc[il], 0, 0, 0);
      }
    }
  }

  float4 bia = *(const float4*)(b_inp + ct * 16 + (lane >> 4) * 4);
  const int co0 = ct * 16 + (lane >> 4) * 4;
  const int colg = J0 + jt;
#pragma unroll
  for (int il = 0; il < 4; ++il) {
    int i = I0 + il;
    float y0 = acc[il][0] + bia.x;
    float y1 = acc[il][1] + bia.y;
    float y2 = acc[il][2] + bia.z;
    float y3 = acc[il][3] + bia.w;
    float s0 = y0 / (1.f + __expf(-y0));
    float s1 = y1 / (1.f + __expf(-y1));
    float s2 = y2 / (1.f + __expf(-y2));
    float s3 = y3 / (1.f + __expf(-y3));
    uint2 uv;
    uv.x = pack2(s0, s1);
    uv.y = pack2(s2, s3);
    *(uint2*)(xbuf + ((size_t)(b * HH + i) * WW + colg) * 32 + co0) = uv;
  }
}

// ---------------------------------------------------------------------------
// Kernel 2 v4: all-MFMA fused. Per tap: ONE b128 B-fragment read feeds THREE
// MFMAs (folded dout, G1, G2). Square = G1*G2 elementwise on accumulator regs
// -> bf16 panel. Phase C: final GEMM K=128 (sq + cen). Phase B VALU deleted.
// ---------------------------------------------------------------------------
#define PPITCH 132

__global__ __launch_bounds__(256, 4) void k_fused(
    const unsigned short* __restrict__ xbuf, const float* __restrict__ cen,
    const unsigned short* __restrict__ wfrag2,
    const unsigned short* __restrict__ wfrag3,
    const unsigned short* __restrict__ wfrag4,
    const unsigned short* __restrict__ wfrag5,
    const float* __restrict__ b_out, float* __restrict__ out) {
  __shared__ alignas(16) unsigned short xs[196 * 36];      // 14.1 KB
  __shared__ alignas(16) unsigned short panel[64][PPITCH]; // 16.9 KB

  const int bx = blockIdx.x;   // 0..15
  const int by = blockIdx.y;   // 0..15
  const int b  = blockIdx.z;
  const int t  = threadIdx.x;
  const int lane = t & 63;
  const int w = t >> 6;
  const int I0 = by * 8, J0 = bx * 8;

  // stage cen -> panel cols k=64..127 (2 ch per u32)
#pragma unroll
  for (int j = 0; j < 8; ++j) {
    int idx = j * 256 + t;
    int cc = idx >> 6, p = idx & 63;
    int py = p >> 3, px = p & 7;
    const float* cp = cen + ((size_t)(b * CIN + 2 * cc) * HH + I0 + py) * WW
                      + J0 + px;
    *(unsigned int*)&panel[p][64 + 2 * cc] = pack2(cp[0], cp[HW]);
  }

  // stage xs: 14x14 halo x 32 ch from channel-interleaved xbuf
  {
    int row = t >> 4, col = t & 15;
    if (row < 14 && col < 14) {
      int gi = I0 - 3 + row, gj = J0 - 3 + col;
      bool ok = (gi >= 0 && gi < HH && gj >= 0 && gj < WW);
      const unsigned short* gp = xbuf +
          ((size_t)((size_t)b * HH + (ok ? gi : 0)) * WW + (ok ? gj : 0)) * 32;
      unsigned short* sp = xs + (row * 14 + col) * 36;
#pragma unroll
      for (int s = 0; s < 4; ++s) {
        uint4 v = make_uint4(0u, 0u, 0u, 0u);
        if (ok) v = *(const uint4*)(gp + 8 * s);
        *(uint2*)(sp + 8 * s)     = make_uint2(v.x, v.y);
        *(uint2*)(sp + 8 * s + 4) = make_uint2(v.z, v.w);
      }
    }
  }
  __syncthreads();

  // ---- Phase A: tap-outer; 1 fragment read -> 3 MFMAs (dout, G1, G2) ----
  f32x4 accD[4], aG1[4], aG2[4];
#pragma unroll
  for (int pt = 0; pt < 4; ++pt) { accD[pt] = 0.f; aG1[pt] = 0.f; aG2[pt] = 0.f; }

  const int prow = lane & 15;
  const int gsh = (lane >> 4) * 8;
#pragma unroll
  for (int ty = 0; ty < 3; ++ty) {
#pragma unroll
    for (int tx = 0; tx < 3; ++tx) {
      const int tap = ty * 3 + tx;
      bf16x8 a3 = ((const bf16x8*)wfrag3)[(tap * 4 + w) * 64 + lane];
      bf16x8 a4 = ((const bf16x8*)wfrag4)[(tap * 4 + w) * 64 + lane];
      bf16x8 a5 = ((const bf16x8*)wfrag5)[(tap * 4 + w) * 64 + lane];
#pragma unroll
      for (int pt = 0; pt < 4; ++pt) {
        int p = pt * 16 + prow;
        int pos = ((p >> 3) + 3 * ty) * 14 + (p & 7) + 3 * tx;
        bf16x8 bfr = *(const bf16x8*)(xs + pos * 36 + gsh);
        accD[pt] = __builtin_amdgcn_mfma_f32_16x16x32_bf16(
            a3, bfr, accD[pt], 0, 0, 0);
        aG1[pt] = __builtin_amdgcn_mfma_f32_16x16x32_bf16(
            a4, bfr, aG1[pt], 0, 0, 0);
        aG2[pt] = __builtin_amdgcn_mfma_f32_16x16x32_bf16(
            a5, bfr, aG2[pt], 0, 0, 0);
      }
    }
  }

  // square = G1*G2 elementwise -> panel sq cols (m = 16w + 4g + r)
  {
    const int colb = w * 16 + (lane >> 4) * 4;
#pragma unroll
    for (int pt = 0; pt < 4; ++pt) {
      int p = pt * 16 + prow;
      float p0 = aG1[pt][0] * aG2[pt][0];
      float p1 = aG1[pt][1] * aG2[pt][1];
      float p2 = aG1[pt][2] * aG2[pt][2];
      float p3 = aG1[pt][3] * aG2[pt][3];
      *(unsigned*)&panel[p][colb]     = pack2(p0, p1);
      *(unsigned*)&panel[p][colb + 2] = pack2(p2, p3);
    }
  }
  __syncthreads();

  // ---- Phase C: final GEMM K=128 over panel (sq + cen) ----
#pragma unroll
  for (int kt = 0; kt < 4; ++kt) {
    bf16x8 a2 = ((const bf16x8*)wfrag2)[(kt * 4 + w) * 64 + lane];
#pragma unroll
    for (int pt = 0; pt < 4; ++pt) {
      bf16x8 bfr = *(const bf16x8*)(&panel[pt * 16 + prow][kt * 32 + gsh]);
      accD[pt] = __builtin_amdgcn_mfma_f32_16x16x32_bf16(
          a2, bfr, accD[pt], 0, 0, 0);
    }
  }

  // epilogue: bias + store fp32
  float4 bo = *(const float4*)(b_out + w * 16 + (lane >> 4) * 4);
#pragma unroll
  for (int pt = 0; pt < 4; ++pt) {
    int p = pt * 16 + prow;
    int ppy = p >> 3, ppx = p & 7;
#pragma unroll
    for (int r = 0; r < 4; ++r) {
      int o = w * 16 + (lane >> 4) * 4 + r;
      out[((b * OUTC + o) * HH + I0 + ppy) * WW + J0 + ppx] =
          accD[pt][r] + ((const float*)&bo)[r];
    }
  }
}

// ---------------------------------------------------------------------------
extern "C" void kernel_launch(void* const* d_in, const int* in_sizes, int n_in,
                              void* d_out, int out_size, void* d_ws, size_t ws_size,
                              hipStream_t stream) {
  const float* cen   = (const float*)d_in[0];
  const float* mas   = (const float*)d_in[1];
  const float* w_inp = (const float*)d_in[2];
  const float* b_inp = (const float*)d_in[3];
  const float* w1    = (const float*)d_in[4];
  const float* w2    = (const float*)d_in[5];
  const float* w3    = (const float*)d_in[6];
  const float* w_out = (const float*)d_in[7];
  const float* b_out = (const float*)d_in[8];
  float* out = (float*)d_out;

  unsigned short* xbuf   = (unsigned short*)d_ws;            // bf16, 16.8 MB
  unsigned short* wfrag  = xbuf + (size_t)BATCH * HW * 32;   // 9216
  unsigned short* wfrag2 = wfrag + 9216;                     // 8192
  unsigned short* wfrag3 = wfrag2 + 8192;                    // 18432
  unsigned short* wfrag4 = wfrag3 + 18432;                   // 18432
  unsigned short* wfrag5 = wfrag4 + 18432;                   // 18432

  hipLaunchKernelGGL(k_prep_weights, dim3(284), dim3(256), 0, stream,
                     w_out, w_inp, w1, w2, w3,
                     wfrag, wfrag2, wfrag3, wfrag4, wfrag5);
  hipLaunchKernelGGL(k_stem, dim3(4, 32, 16), dim3(256), 0, stream,
                     mas, wfrag, b_inp, xbuf);
  hipLaunchKernelGGL(k_fused, dim3(16, 16, 16), dim3(256), 0, stream,
                     xbuf, cen, wfrag2, wfrag3, wfrag4, wfrag5, b_out, out);
}

// Round 10
// 110.485 us; speedup vs baseline: 1.3612x; 1.3612x over previous
//
#include <hip/hip_runtime.h>
#include <hip/hip_bf16.h>

// Problem constants
#define BATCH 16
#define CH    32      // depthwise group count
#define CIN   64
#define OUTC  64
#define HH    128     // h after stride-2 stem
#define WW    128
#define HW    (HH * WW)
#define MHW   65536   // mas plane 256*256

typedef __attribute__((ext_vector_type(8))) short bf16x8;
typedef __attribute__((ext_vector_type(4))) float f32x4;

__device__ inline unsigned short bf16u(float x) {
  union { __hip_bfloat16 h; unsigned short s; } u;
  u.h = __float2bfloat16(x);
  return u.s;
}
__device__ inline unsigned int pack2(float lo, float hi) {
  return (unsigned int)bf16u(lo) | ((unsigned int)bf16u(hi) << 16);
}
__device__ inline float losf(unsigned u) { return __uint_as_float(u << 16); }
__device__ inline float hisf(unsigned u) { return __uint_as_float(u & 0xffff0000u); }

// ---------------------------------------------------------------------------
// Kernel 0: weight prep (bf16 MFMA A-fragments). Same as round 6/7.
//  - wfrag  [9][2][64][8]: stem w_inp
//  - wfrag2 [4][4][64][8]: final GEMM K=128 (k<64 sq, k>=64 cen)
//  - wfrag3 [9][4][64][8]: folded dout conv W9[tap][o][C]
// ---------------------------------------------------------------------------
__global__ __launch_bounds__(256) void k_prep_weights(
    const float* __restrict__ w_out, const float* __restrict__ w_inp,
    const float* __restrict__ w3,
    unsigned short* __restrict__ wfrag, unsigned short* __restrict__ wfrag2,
    unsigned short* __restrict__ wfrag3) {
  int t = blockIdx.x * 256 + threadIdx.x;
  if (t < 9 * 2 * 64 * 8) {
    int e    = t & 7;
    int lane = (t >> 3) & 63;
    int ct   = (t >> 9) & 1;
    int tap  = t >> 10;
    int co = ct * 16 + (lane & 15);
    int ci = (lane >> 4) * 8 + e;
    wfrag[t] = bf16u(w_inp[(co * CH + ci) * 9 + tap]);
  }
  int t2 = t - 9216;
  if (t2 >= 0 && t2 < 8192) {
    int e    = t2 & 7;
    int lane = (t2 >> 3) & 63;
    int ot   = (t2 >> 9) & 3;
    int kt   = t2 >> 11;
    int o = ot * 16 + (lane & 15);
    int k = kt * 32 + (lane >> 4) * 8 + e;
    int col = (k < 64) ? k : 64 + k;   // sq block 0..63, cen block 128..191
    wfrag2[t2] = bf16u(w_out[o * 192 + col]);
  }
  int t3 = t - 17408;
  if (t3 >= 0 && t3 < 18432) {
    int e    = t3 & 7;
    int lane = (t3 >> 3) & 63;
    int ot   = (t3 >> 9) & 3;
    int tap  = t3 >> 11;
    int o = ot * 16 + (lane & 15);
    int C = (lane >> 4) * 8 + e;
    const int kmap[9] = {0, 1, 2, 7, -1, 3, 6, 5, 4};
    float v = 0.f;
    if (tap == 4) {
      for (int k = 0; k < 8; ++k)
        for (int op = 0; op < 2; ++op)
          v += w_out[o * 192 + 64 + 2 * C + op] * w3[C * 16 + op * 8 + k];
    } else {
      int k = kmap[tap];
      for (int op = 0; op < 2; ++op)
        v -= w_out[o * 192 + 64 + 2 * C + op] * w3[C * 16 + op * 8 + k];
    }
    wfrag3[t3] = bf16u(v);
  }
}

// ---------------------------------------------------------------------------
// Kernel 1 v4: stem via bf16 MFMA. Round-7 structure +
//  (a) XCD-chunked block swizzle (bx-adjacent tiles share an XCD L2),
//  (b) staging spread over all 256 threads (306 half-ci tasks, was 153x32).
// ---------------------------------------------------------------------------
#define BEE 0
#define BEO 165
#define BOE 330
#define BOO 462
#define SPITCH 36

__global__ __launch_bounds__(256, 3) void k_stem(
    const float* __restrict__ mas, const unsigned short* __restrict__ wfrag,
    const float* __restrict__ b_inp, unsigned short* __restrict__ xbuf) {
  __shared__ alignas(16) unsigned short xs[594 * SPITCH];

  // XCD swizzle: 2048 blocks = 8 XCD x 256
  const int W = blockIdx.x + 4 * blockIdx.y + 128 * blockIdx.z;
  const int F = (W & 7) * 256 + (W >> 3);
  const int bx = F & 3;          // col tile of 32
  const int by = (F >> 2) & 31;  // row tile of 4
  const int b  = F >> 7;         // batch

  const int t  = threadIdx.x;
  const int lane = t & 63;
  const int w = t >> 6;
  const int ct = w >> 1, chh = w & 1;

  const int I0 = by * 4, J0 = bx * 32;
  const int R0 = 2 * I0 - 1, C0 = 2 * J0 - 1;

  // A-fragments for this wave's co-tile
  bf16x8 af[9];
#pragma unroll
  for (int tap = 0; tap < 9; ++tap)
    af[tap] = ((const bf16x8*)wfrag)[(tap * 2 + ct) * 64 + lane];

  // ---- staging: 306 tasks = (153 cells) x (2 ci-halves) over 256 thr ----
  for (int task = t; task < 306; task += 256) {
    int cellIdx = task >> 1;
    int cib = (task & 1) * 16;   // ci base for this half
    if (cellIdx < 144) {
      int chunk = cellIdx / 9, rr = cellIdx % 9;
      int cc0 = 1 + 4 * chunk;
      int ir = R0 + rr;
      bool vrow = (ir >= 0);
      const float* gp = mas + (size_t)b * CH * MHW +
                        (size_t)(vrow ? ir : 0) * 256 + (C0 + cc0);
      int off[4];
#pragma unroll
      for (int j = 0; j < 4; ++j) {
        int cc = cc0 + j;
        int r2 = rr >> 1;
        int pix;
        if (!(rr & 1))
          pix = (cc & 1) ? BEO + r2 * 33 + ((cc - 1) >> 1)
                         : BEE + r2 * 33 + (cc >> 1);
        else
          pix = (cc & 1) ? BOO + r2 * 33 + ((cc - 1) >> 1)
                         : BOE + r2 * 33 + (cc >> 1);
        off[j] = pix * SPITCH;
      }
#pragma unroll 4
      for (int q = 0; q < 8; ++q) {
        int ci = cib + 2 * q;
        float4 v0 = make_float4(0.f, 0.f, 0.f, 0.f);
        float4 v1 = v0;
        if (vrow) {
          v0 = *(const float4*)(gp + (size_t)ci * MHW);
          v1 = *(const float4*)(gp + (size_t)(ci + 1) * MHW);
        }
        *(unsigned*)&xs[off[0] + ci] = pack2(v0.x, v1.x);
        *(unsigned*)&xs[off[1] + ci] = pack2(v0.y, v1.y);
        *(unsigned*)&xs[off[2] + ci] = pack2(v0.z, v1.z);
        *(unsigned*)&xs[off[3] + ci] = pack2(v0.w, v1.w);
      }
    } else {
      int rr = cellIdx - 144;
      int ir = R0 + rr;
      bool ok = (ir >= 0) && (bx > 0);
      int r2 = rr >> 1;
      int pix = (rr & 1) ? (BOE + r2 * 33) : (BEE + r2 * 33);
      const float* gp = mas + (size_t)b * CH * MHW +
                        (size_t)(ir >= 0 ? ir : 0) * 256 + (C0 >= 0 ? C0 : 0);
      int off0 = pix * SPITCH;
#pragma unroll 4
      for (int q = 0; q < 8; ++q) {
        int ci = cib + 2 * q;
        float a0 = 0.f, a1 = 0.f;
        if (ok) {
          a0 = gp[(size_t)ci * MHW];
          a1 = gp[(size_t)(ci + 1) * MHW];
        }
        *(unsigned*)&xs[off0 + ci] = pack2(a0, a1);
      }
    }
  }
  __syncthreads();

  // ---- compute: wave covers cols [J0+16ch,+16), co [16ct,+16), 4 rows ----
  f32x4 acc[4];
#pragma unroll
  for (int il = 0; il < 4; ++il) acc[il] = 0.f;

  const int jt = chh * 16 + (lane & 15);
  const int gsh = (lane >> 4) * 8;

#pragma unroll
  for (int ky = 0; ky < 3; ++ky) {
#pragma unroll
    for (int kx = 0; kx < 3; ++kx) {
      const int tap = ky * 3 + kx;
#pragma unroll
      for (int il = 0; il < 4; ++il) {
        int pix;
        if (ky == 1) {
          pix = (kx == 1) ? (BOO + il * 33 + jt)
                          : (BOE + il * 33 + jt + (kx == 2));
        } else {
          int r2 = il + (ky >> 1);
          pix = (kx == 1) ? (BEO + r2 * 33 + jt)
                          : (BEE + r2 * 33 + jt + (kx == 2));
        }
        bf16x8 bfr = *(const bf16x8*)(xs + pix * SPITCH + gsh);
        acc[il] = __builtin_amdgcn_mfma_f32_16x16x32_bf16(
            af[tap], bfr, acc[il], 0, 0, 0);
      }
    }
  }

  // ---- epilogue: bias + SiLU, store bf16 channel-interleaved ----
  float4 bia = *(const float4*)(b_inp + ct * 16 + (lane >> 4) * 4);
  const int co0 = ct * 16 + (lane >> 4) * 4;
  const int colg = J0 + jt;
#pragma unroll
  for (int il = 0; il < 4; ++il) {
    int i = I0 + il;
    float y0 = acc[il][0] + bia.x;
    float y1 = acc[il][1] + bia.y;
    float y2 = acc[il][2] + bia.z;
    float y3 = acc[il][3] + bia.w;
    float s0 = y0 / (1.f + __expf(-y0));
    float s1 = y1 / (1.f + __expf(-y1));
    float s2 = y2 / (1.f + __expf(-y2));
    float s3 = y3 / (1.f + __expf(-y3));
    uint2 uv;
    uv.x = pack2(s0, s1);
    uv.y = pack2(s2, s3);
    *(uint2*)(xbuf + ((size_t)(b * HH + i) * WW + colg) * 32 + co0) = uv;
  }
}

// ---------------------------------------------------------------------------
// Kernel 2 v3 (reverted from v4): folded-dout MFMA + VALU square gates +
// final GEMM K=128. + XCD-chunked swizzle.
// ---------------------------------------------------------------------------
#define PPITCH 132

__global__ __launch_bounds__(256, 4) void k_fused(
    const unsigned short* __restrict__ xbuf, const float* __restrict__ cen,
    const float* __restrict__ w1, const float* __restrict__ w2,
    const unsigned short* __restrict__ wfrag2,
    const unsigned short* __restrict__ wfrag3,
    const float* __restrict__ b_out, float* __restrict__ out) {
  __shared__ alignas(16) unsigned short xs[196 * 36];      // 14.1 KB
  __shared__ alignas(16) unsigned short panel[64][PPITCH]; // 16.9 KB

  // XCD swizzle: 4096 blocks = 8 XCD x 512; bx-adjacent tiles co-XCD
  const int W = blockIdx.x + 16 * blockIdx.y + 256 * blockIdx.z;
  const int F = (W & 7) * 512 + (W >> 3);
  const int bx = F & 15;
  const int by = (F >> 4) & 15;
  const int b  = F >> 8;

  const int t  = threadIdx.x;
  const int lane = t & 63;
  const int w = t >> 6;
  const int I0 = by * 8, J0 = bx * 8;

  // A-fragments for this wave's o-tile
  bf16x8 af3[9], af2[4];
#pragma unroll
  for (int tap = 0; tap < 9; ++tap)
    af3[tap] = ((const bf16x8*)wfrag3)[(tap * 4 + w) * 64 + lane];
#pragma unroll
  for (int kt = 0; kt < 4; ++kt)
    af2[kt] = ((const bf16x8*)wfrag2)[(kt * 4 + w) * 64 + lane];

  // stage cen -> panel cols k=64..127 (2 ch per u32)
#pragma unroll
  for (int j = 0; j < 8; ++j) {
    int idx = j * 256 + t;
    int cc = idx >> 6, p = idx & 63;
    int py = p >> 3, px = p & 7;
    const float* cp = cen + ((size_t)(b * CIN + 2 * cc) * HH + I0 + py) * WW
                      + J0 + px;
    *(unsigned int*)&panel[p][64 + 2 * cc] = pack2(cp[0], cp[HW]);
  }

  // stage xs: 14x14 halo x 32 ch from channel-interleaved xbuf
  {
    int row = t >> 4, col = t & 15;
    if (row < 14 && col < 14) {
      int gi = I0 - 3 + row, gj = J0 - 3 + col;
      bool ok = (gi >= 0 && gi < HH && gj >= 0 && gj < WW);
      const unsigned short* gp = xbuf +
          ((size_t)((size_t)b * HH + (ok ? gi : 0)) * WW + (ok ? gj : 0)) * 32;
      unsigned short* sp = xs + (row * 14 + col) * 36;
#pragma unroll
      for (int s = 0; s < 4; ++s) {
        uint4 v = make_uint4(0u, 0u, 0u, 0u);
        if (ok) v = *(const uint4*)(gp + 8 * s);
        *(uint2*)(sp + 8 * s)     = make_uint2(v.x, v.y);
        *(uint2*)(sp + 8 * s + 4) = make_uint2(v.z, v.w);
      }
    }
  }
  __syncthreads();

  // ---- Phase A: folded-dout 9-tap dilated conv via MFMA ----
  f32x4 acc[4];
#pragma unroll
  for (int pt = 0; pt < 4; ++pt) acc[pt] = 0.f;

  const int prow = lane & 15;
  const int gsh = (lane >> 4) * 8;
#pragma unroll
  for (int pt = 0; pt < 4; ++pt) {
    int p = pt * 16 + prow;
    int ppy = p >> 3, ppx = p & 7;
#pragma unroll
    for (int ty = 0; ty < 3; ++ty)
#pragma unroll
      for (int tx = 0; tx < 3; ++tx) {
        int pos = (ppy + 3 * ty) * 14 + ppx + 3 * tx;
        bf16x8 bfr = *(const bf16x8*)(xs + pos * 36 + gsh);
        acc[pt] = __builtin_amdgcn_mfma_f32_16x16x32_bf16(
            af3[ty * 3 + tx], bfr, acc[pt], 0, 0, 0);
      }
  }

  // ---- Phase B: square gates (VALU), dual-channel tasks ----
  {
    const int py = lane >> 3, px = lane & 7;
    const int posc = (py + 3) * 14 + (px + 3);
    int pos8[8];
    pos8[0] = (py + 0) * 14 + px + 0;   // (-3,-3)
    pos8[1] = (py + 0) * 14 + px + 3;   // (-3, 0)
    pos8[2] = (py + 0) * 14 + px + 6;   // (-3, 3)
    pos8[3] = (py + 3) * 14 + px + 6;   // ( 0, 3)
    pos8[4] = (py + 6) * 14 + px + 6;   // ( 3, 3)
    pos8[5] = (py + 6) * 14 + px + 3;   // ( 3, 0)
    pos8[6] = (py + 6) * 14 + px + 0;   // ( 3,-3)
    pos8[7] = (py + 3) * 14 + px + 0;   // ( 0,-3)

#pragma unroll
    for (int j = 0; j < 4; ++j) {
      int c2 = __builtin_amdgcn_readfirstlane(j * 4 + w);  // 0..15
      const float* w1lo = w1 + (2 * c2) * 16;       // wave-uniform (scalar)
      const float* w1hi = w1 + (2 * c2 + 1) * 16;
      const float* w2lo = w2 + (2 * c2) * 16;
      const float* w2hi = w2 + (2 * c2 + 1) * 16;
      unsigned uc = *(const unsigned*)(xs + posc * 36 + 2 * c2);
      float clo = losf(uc), chi = hisf(uc);
      float g1l0 = 0, g1l1 = 0, g2l0 = 0, g2l1 = 0;
      float g1h0 = 0, g1h1 = 0, g2h0 = 0, g2h1 = 0;
#pragma unroll
      for (int k = 0; k < 8; ++k) {
        unsigned us = *(const unsigned*)(xs + pos8[k] * 36 + 2 * c2);
        float dlo = clo - losf(us);
        float dhi = chi - hisf(us);
        g1l0 += dlo * w1lo[k];  g1l1 += dlo * w1lo[8 + k];
        g2l0 += dlo * w2lo[k];  g2l1 += dlo * w2lo[8 + k];
        g1h0 += dhi * w1hi[k];  g1h1 += dhi * w1hi[8 + k];
        g2h0 += dhi * w2hi[k];  g2h1 += dhi * w2hi[8 + k];
      }
      uint2 wv;
      wv.x = pack2(g1l0 * g2l0, g1l1 * g2l1);
      wv.y = pack2(g1h0 * g2h0, g1h1 * g2h1);
      *(uint2*)&panel[lane][4 * c2] = wv;   // sq cols 4c2..4c2+3
    }
  }
  __syncthreads();

  // ---- Phase C: final GEMM K=128 over panel (sq + cen) ----
#pragma unroll
  for (int pt = 0; pt < 4; ++pt) {
#pragma unroll
    for (int kt = 0; kt < 4; ++kt) {
      bf16x8 bfr = *(const bf16x8*)(&panel[pt * 16 + prow][kt * 32 + gsh]);
      acc[pt] = __builtin_amdgcn_mfma_f32_16x16x32_bf16(
          af2[kt], bfr, acc[pt], 0, 0, 0);
    }
  }

  // epilogue: bias + store fp32
  float4 bo = *(const float4*)(b_out + w * 16 + (lane >> 4) * 4);
#pragma unroll
  for (int pt = 0; pt < 4; ++pt) {
    int p = pt * 16 + prow;
    int ppy = p >> 3, ppx = p & 7;
#pragma unroll
    for (int r = 0; r < 4; ++r) {
      int o = w * 16 + (lane >> 4) * 4 + r;
      out[((b * OUTC + o) * HH + I0 + ppy) * WW + J0 + ppx] =
          acc[pt][r] + ((const float*)&bo)[r];
    }
  }
}

// ---------------------------------------------------------------------------
extern "C" void kernel_launch(void* const* d_in, const int* in_sizes, int n_in,
                              void* d_out, int out_size, void* d_ws, size_t ws_size,
                              hipStream_t stream) {
  const float* cen   = (const float*)d_in[0];
  const float* mas   = (const float*)d_in[1];
  const float* w_inp = (const float*)d_in[2];
  const float* b_inp = (const float*)d_in[3];
  const float* w1    = (const float*)d_in[4];
  const float* w2    = (const float*)d_in[5];
  const float* w3    = (const float*)d_in[6];
  const float* w_out = (const float*)d_in[7];
  const float* b_out = (const float*)d_in[8];
  float* out = (float*)d_out;

  unsigned short* xbuf   = (unsigned short*)d_ws;            // bf16, 16.8 MB
  unsigned short* wfrag  = xbuf + (size_t)BATCH * HW * 32;   // 9216
  unsigned short* wfrag2 = wfrag + 9216;                     // 8192
  unsigned short* wfrag3 = wfrag2 + 8192;                    // 18432

  hipLaunchKernelGGL(k_prep_weights, dim3(140), dim3(256), 0, stream,
                     w_out, w_inp, w3, wfrag, wfrag2, wfrag3);
  hipLaunchKernelGGL(k_stem, dim3(4, 32, 16), dim3(256), 0, stream,
                     mas, wfrag, b_inp, xbuf);
  hipLaunchKernelGGL(k_fused, dim3(16, 16, 16), dim3(256), 0, stream,
                     xbuf, cen, w1, w2, wfrag2, wfrag3, b_out, out);
}